// Round 8
// baseline (1345.995 us; speedup 1.0000x reference)
//
#include <hip/hip_runtime.h>
#include <hip/hip_bf16.h>

typedef __bf16 bf16x8 __attribute__((ext_vector_type(8)));
typedef float  f32x4  __attribute__((ext_vector_type(4)));

#define V_TOTAL 32768
#define NT      256        // 4 waves; wave owns 64 M-rows; aa[8][4]=128 VGPRs
#define NV      16         // v-chunks of 64 positions per block
#define NBLK    512        // = 2 blocks/CU exactly; 32 blocks per sample

// ---- prep: w2 fp32 -> bf16 (RNE) into workspace ----
__global__ void w2_to_bf16(const float* __restrict__ w2, __bf16* __restrict__ w2b) {
    int i = blockIdx.x * 256 + threadIdx.x;   // grid sized exactly: 8*256*256
    w2b[i] = (__bf16)w2[i];
}

__global__ __launch_bounds__(NT)
__attribute__((amdgpu_waves_per_eu(2, 2)))   // pin: VGPR budget = 512/2 = 256, no spill
void fused_mlp(
    const float* __restrict__ x,  const int* __restrict__ obj,
    const float* __restrict__ w1, const float* __restrict__ b1,
    const float* __restrict__ b2, const float* __restrict__ w3,
    const float* __restrict__ b3, const __bf16* __restrict__ w2b,
    float* __restrict__ out)
{
    // h1t: [64 pos][32 chunks of 16B], chunk slot XOR-swizzled by (pos&7)
    __shared__ __align__(16) char h1t[32768];
    __shared__ float red[256];          // 4 waves x 64 L3 partials

    const int t    = threadIdx.x;
    const int lane = t & 63;
    const int wv   = t >> 6;            // wave owns M rows [wv*64, wv*64+64)
    const int llo  = lane & 15;
    const int lhi  = lane >> 4;
    const int b    = blockIdx.x >> 5;   // sample (32 blocks each)
    const int g    = blockIdx.x & 31;   // 1024-position group
    const int e    = __builtin_amdgcn_readfirstlane(obj[b]);

    // ---- W2 A-fragments: 64 rows x K=256 per wave = 128 VGPRs, loaded ONCE ----
    const __bf16* w2e = w2b + (size_t)e * 65536;
    bf16x8 aa[8][4];
    #pragma unroll
    for (int kt = 0; kt < 8; ++kt)
        #pragma unroll
        for (int mt = 0; mt < 4; ++mt) {
            int m = wv * 64 + mt * 16 + llo;          // A[m][kt*32+lhi*8+j]
            aa[kt][mt] = *(const bf16x8*)(w2e + m * 256 + kt * 32 + lhi * 8);
        }

    const float* w1e = w1 + e * 1536;   // uniform bases -> scalar loads in L1
    const float* b1e = b1 + e * 256;
    const float  b3e = b3[e];
    const int    nx  = lane & 7;

    float xr[6];                        // chunk 0 inputs
    #pragma unroll
    for (int i = 0; i < 6; ++i)
        xr[i] = x[(size_t)(b * 6 + i) * V_TOTAL + g * (NV * 64) + lane];

    for (int iv = 0; iv < NV; ++iv) {
        const int v0 = (g * NV + iv) * 64;

        // ---- layer 1: h1t[pos][k] = relu(W1 x + b1); 8 chunks of 8 per wave ----
        {
            char* drow = h1t + lane * 512;
            #pragma unroll
            for (int q = 0; q < 8; ++q) {
                int m8 = wv * 8 + q;                  // 16B chunk (8 h-values)
                bf16x8 pack;
                #pragma unroll
                for (int j = 0; j < 8; ++j) {
                    int m = m8 * 8 + j;               // uniform -> scalar operands
                    float a = b1e[m];
                    #pragma unroll
                    for (int i2 = 0; i2 < 6; ++i2)
                        a = fmaf(w1e[m * 6 + i2], xr[i2], a);
                    pack[j] = (__bf16)fmaxf(a, 0.f);
                }
                *(bf16x8*)(drow + ((m8 ^ nx) << 4)) = pack;
            }
        }
        __syncthreads();   // h1 ready

        if (iv + 1 < NV)   // prefetch next chunk's x under the MFMA phase
            #pragma unroll
            for (int i = 0; i < 6; ++i)
                xr[i] = x[(size_t)(b * 6 + i) * V_TOTAL + v0 + 64 + lane];

        // ---- layer 2: 128 MFMA/wave vs LDS B-frags; A from registers ----
        f32x4 acc[4][4];
        #pragma unroll
        for (int mt = 0; mt < 4; ++mt) {              // init = bias b2 (L1$-hot)
            f32x4 bv = *(const f32x4*)(b2 + e * 256 + wv * 64 + mt * 16 + lhi * 4);
            #pragma unroll
            for (int nt = 0; nt < 4; ++nt) acc[mt][nt] = bv;
        }
        #pragma unroll
        for (int kt = 0; kt < 8; ++kt) {
            bf16x8 bb[4];
            #pragma unroll
            for (int nt = 0; nt < 4; ++nt) {          // conflict-free via swizzle
                int n = nt * 16 + llo;
                bb[nt] = *(const bf16x8*)(h1t + n * 512 + (((kt * 4 + lhi) ^ (n & 7)) << 4));
            }
            #pragma unroll
            for (int mt = 0; mt < 4; ++mt)
                #pragma unroll
                for (int nt = 0; nt < 4; ++nt)
                    acc[mt][nt] = __builtin_amdgcn_mfma_f32_16x16x32_bf16(
                        aa[kt][mt], bb[nt], acc[mt][nt], 0, 0, 0);
        }

        // ---- layer 3: out[n] = sum_m w3[m]*relu(h2[m][n]) + b3 ----
        float p[4];
        #pragma unroll
        for (int nt = 0; nt < 4; ++nt) {
            float s = 0.f;
            #pragma unroll
            for (int mt = 0; mt < 4; ++mt) {          // w3 reload: L1$-hot, saves VGPRs
                f32x4 wf = *(const f32x4*)(w3 + e * 256 + wv * 64 + mt * 16 + lhi * 4);
                #pragma unroll
                for (int j = 0; j < 4; ++j)
                    s = fmaf(wf[j], fmaxf(acc[mt][nt][j], 0.f), s);
            }
            s += __shfl_xor(s, 16, 64);
            s += __shfl_xor(s, 32, 64);
            p[nt] = s;                                // lanes 0-15 hold n=nt*16+lane
        }
        if (lane < 16)
            #pragma unroll
            for (int nt = 0; nt < 4; ++nt)
                red[wv * 64 + nt * 16 + lane] = p[nt];
        __syncthreads();   // red ready AND all h1t reads done (safe to overwrite)
        if (t < 64)
            out[(size_t)b * V_TOTAL + v0 + t] =
                red[t] + red[64 + t] + red[128 + t] + red[192 + t] + b3e;
        // red reads finish before the next chunk's post-L1 barrier -> safe
    }
}

extern "C" void kernel_launch(void* const* d_in, const int* in_sizes, int n_in,
                              void* d_out, int out_size, void* d_ws, size_t ws_size,
                              hipStream_t stream) {
    const float* x   = (const float*)d_in[0];
    const int*   obj = (const int*)d_in[1];
    const float* w1  = (const float*)d_in[2];
    const float* b1  = (const float*)d_in[3];
    const float* w2  = (const float*)d_in[4];
    const float* b2  = (const float*)d_in[5];
    const float* w3  = (const float*)d_in[6];
    const float* b3  = (const float*)d_in[7];
    float*  out = (float*)d_out;
    __bf16* w2b = (__bf16*)d_ws;   // 8*256*256 bf16 = 1 MB

    w2_to_bf16<<<2048, 256, 0, stream>>>(w2, w2b);
    fused_mlp<<<NBLK, NT, 0, stream>>>(x, obj, w1, b1, b2, w3, b3, w2b, out);
}

// Round 10
// 1073.344 us; speedup vs baseline: 1.2540x; 1.2540x over previous
//
#include <hip/hip_runtime.h>
#include <hip/hip_bf16.h>

typedef __bf16 bf16x8 __attribute__((ext_vector_type(8)));
typedef float  f32x4  __attribute__((ext_vector_type(4)));

#define V_TOTAL 32768
#define NT      256        // 4 waves; wave owns 64 M-rows; aa[8][4]=128 AGPRs
#define NV      16         // v-chunks of 64 positions per block
#define NBLK    512        // 2 blocks/CU exactly; 32 blocks per sample

// ---- prep: w2 fp32 -> bf16 (RNE) into workspace ----
__global__ void w2_to_bf16(const float* __restrict__ w2, __bf16* __restrict__ w2b) {
    int i = blockIdx.x * 256 + threadIdx.x;   // grid sized exactly: 8*256*256
    w2b[i] = (__bf16)w2[i];
}

__global__ __launch_bounds__(NT)
__attribute__((amdgpu_waves_per_eu(2, 2)))   // total budget 256/wave: 128 arch + 128 agpr
void fused_mlp(
    const float* __restrict__ x,  const int* __restrict__ obj,
    const float* __restrict__ w1, const float* __restrict__ b1,
    const float* __restrict__ b2, const float* __restrict__ w3,
    const float* __restrict__ b3, const __bf16* __restrict__ w2b,
    float* __restrict__ out)
{
    // h1t: [64 pos][32 chunks of 16B], chunk slot XOR-swizzled by (pos&7)
    __shared__ __align__(16) char h1t[32768];
    __shared__ float red[256];          // 4 waves x 64 L3 partials

    const int t    = threadIdx.x;
    const int lane = t & 63;
    const int wv   = t >> 6;            // wave owns M rows [wv*64, wv*64+64)
    const int llo  = lane & 15;
    const int lhi  = lane >> 4;
    const int b    = blockIdx.x >> 5;   // sample (32 blocks each)
    const int g    = blockIdx.x & 31;   // 1024-position group
    const int e    = __builtin_amdgcn_readfirstlane(obj[b]);

    // ---- W2 A-fragments: 64 rows x K=256 per wave, loaded ONCE.
    // Used ONLY as inline-asm "a" operands -> allocator assigns AGPR class,
    // relieving the 128-ArchVGPR budget (the R5/R7/R8 spill cause).
    const __bf16* w2e = w2b + (size_t)e * 65536;
    bf16x8 aa[8][4];
    #pragma unroll
    for (int kt = 0; kt < 8; ++kt)
        #pragma unroll
        for (int mt = 0; mt < 4; ++mt) {
            int m = wv * 64 + mt * 16 + llo;          // A[m][kt*32+lhi*8+j]
            aa[kt][mt] = *(const bf16x8*)(w2e + m * 256 + kt * 32 + lhi * 8);
        }

    const float* w1e = w1 + e * 1536;   // uniform bases -> scalar loads in L1
    const float* b1e = b1 + e * 256;
    const float  b3e = b3[e];
    const int    nx  = lane & 7;

    float xr[6];                        // chunk 0 inputs
    #pragma unroll
    for (int i = 0; i < 6; ++i)
        xr[i] = x[(size_t)(b * 6 + i) * V_TOTAL + g * (NV * 64) + lane];

    for (int iv = 0; iv < NV; ++iv) {
        const int v0 = (g * NV + iv) * 64;

        // ---- layer 1: h1t[pos][k] = relu(W1 x + b1); 8 chunks of 8 per wave ----
        {
            char* drow = h1t + lane * 512;
            #pragma unroll
            for (int q = 0; q < 8; ++q) {
                int m8 = wv * 8 + q;                  // 16B chunk (8 h-values)
                bf16x8 pack;
                #pragma unroll
                for (int j = 0; j < 8; ++j) {
                    int m = m8 * 8 + j;               // uniform -> scalar operands
                    float a = b1e[m];
                    #pragma unroll
                    for (int i2 = 0; i2 < 6; ++i2)
                        a = fmaf(w1e[m * 6 + i2], xr[i2], a);
                    pack[j] = (__bf16)fmaxf(a, 0.f);
                }
                *(bf16x8*)(drow + ((m8 ^ nx) << 4)) = pack;
            }
        }
        __syncthreads();   // h1 ready

        if (iv + 1 < NV)   // prefetch next chunk's x under the MFMA phase
            #pragma unroll
            for (int i = 0; i < 6; ++i)
                xr[i] = x[(size_t)(b * 6 + i) * V_TOTAL + v0 + 64 + lane];

        // ---- layer 2: 128 MFMA/wave; A from AGPRs, B from LDS, acc in VGPRs ----
        f32x4 acc[4][4];
        #pragma unroll
        for (int mt = 0; mt < 4; ++mt) {              // init = bias b2 (L1$-hot)
            f32x4 bv = *(const f32x4*)(b2 + e * 256 + wv * 64 + mt * 16 + lhi * 4);
            #pragma unroll
            for (int nt = 0; nt < 4; ++nt) acc[mt][nt] = bv;
        }
        #pragma unroll
        for (int kt = 0; kt < 8; ++kt) {
            bf16x8 bb[4];
            #pragma unroll
            for (int nt = 0; nt < 4; ++nt) {          // conflict-free via swizzle
                int n = nt * 16 + llo;
                bb[nt] = *(const bf16x8*)(h1t + n * 512 + (((kt * 4 + lhi) ^ (n & 7)) << 4));
            }
            #pragma unroll
            for (int mt = 0; mt < 4; ++mt)
                #pragma unroll
                for (int nt = 0; nt < 4; ++nt)
                    asm("v_mfma_f32_16x16x32_bf16 %0, %1, %2, %0"
                        : "+v"(acc[mt][nt])
                        : "a"(aa[kt][mt]), "v"(bb[nt]));
        }

        // ---- layer 3: out[n] = sum_m w3[m]*relu(h2[m][n]) + b3 ----
        float p[4];
        #pragma unroll
        for (int nt = 0; nt < 4; ++nt) {
            float s = 0.f;
            #pragma unroll
            for (int mt = 0; mt < 4; ++mt) {          // w3 reload: L1$-hot, saves VGPRs
                f32x4 wf = *(const f32x4*)(w3 + e * 256 + wv * 64 + mt * 16 + lhi * 4);
                #pragma unroll
                for (int j = 0; j < 4; ++j)
                    s = fmaf(wf[j], fmaxf(acc[mt][nt][j], 0.f), s);
            }
            s += __shfl_xor(s, 16, 64);
            s += __shfl_xor(s, 32, 64);
            p[nt] = s;                                // lanes 0-15 hold n=nt*16+lane
        }
        if (lane < 16)
            #pragma unroll
            for (int nt = 0; nt < 4; ++nt)
                red[wv * 64 + nt * 16 + lane] = p[nt];
        __syncthreads();   // red ready AND all h1t reads done (safe to overwrite)
        if (t < 64)
            out[(size_t)b * V_TOTAL + v0 + t] =
                red[t] + red[64 + t] + red[128 + t] + red[192 + t] + b3e;
        // red reads finish before the next chunk's post-L1 barrier -> safe
    }
}

extern "C" void kernel_launch(void* const* d_in, const int* in_sizes, int n_in,
                              void* d_out, int out_size, void* d_ws, size_t ws_size,
                              hipStream_t stream) {
    const float* x   = (const float*)d_in[0];
    const int*   obj = (const int*)d_in[1];
    const float* w1  = (const float*)d_in[2];
    const float* b1  = (const float*)d_in[3];
    const float* w2  = (const float*)d_in[4];
    const float* b2  = (const float*)d_in[5];
    const float* w3  = (const float*)d_in[6];
    const float* b3  = (const float*)d_in[7];
    float*  out = (float*)d_out;
    __bf16* w2b = (__bf16*)d_ws;   // 8*256*256 bf16 = 1 MB

    w2_to_bf16<<<2048, 256, 0, stream>>>(w2, w2b);
    fused_mlp<<<NBLK, NT, 0, stream>>>(x, obj, w1, b1, b2, w3, b3, w2b, out);
}

// Round 11
// 309.480 us; speedup vs baseline: 4.3492x; 3.4682x over previous
//
#include <hip/hip_runtime.h>
#include <hip/hip_bf16.h>

typedef __bf16 bf16x8 __attribute__((ext_vector_type(8)));
typedef float  f32x4  __attribute__((ext_vector_type(4)));

#define V_TOTAL 32768
#define NT      512        // 8 waves; wave owns 32 M-rows (A read from LDS, not regs)
#define NV      32         // v-chunks of 64 positions per block
#define NBLK    256        // 1 block/CU (LDS-bound); 16 blocks per sample

#define W2_LDS  131072     // [8 kt][256 m][4 sl] chunks of 16B -> frag-linear A reads
#define H1_LDS  32768      // [64 pos][32 c] chunks, c = m8 ^ (pos&7)
#define LDS_TOT (W2_LDS + H1_LDS)   // 163840 = 160 KiB exactly

// async global->LDS, 16B/lane; LDS dest = wave-uniform base + lane*16
#define GLOAD_LDS16(g, l) __builtin_amdgcn_global_load_lds( \
    (const __attribute__((address_space(1))) void*)(g),     \
    (__attribute__((address_space(3))) void*)(l), 16, 0, 0)

// ---- prep: w2 fp32 -> bf16 (RNE) into workspace ----
__global__ void w2_to_bf16(const float* __restrict__ w2, __bf16* __restrict__ w2b) {
    int i = blockIdx.x * 256 + threadIdx.x;   // grid sized exactly: 8*256*256
    w2b[i] = (__bf16)w2[i];
}

__global__ __launch_bounds__(NT) void fused_mlp(
    const float* __restrict__ x,  const int* __restrict__ obj,
    const float* __restrict__ w1, const float* __restrict__ b1,
    const float* __restrict__ b2, const float* __restrict__ w3,
    const float* __restrict__ b3, const __bf16* __restrict__ w2b,
    float* __restrict__ out)
{
    extern __shared__ __align__(16) char smem[];
    char*  w2s = smem;            // A: chunk (kt*1024 + m*4 + sl) holds W2[m][kt*32+sl*8 ..+8)
    char*  h1t = smem + W2_LDS;   // B: row pos, chunk slot m8 ^ (pos&7)
    float* red = (float*)h1t;     // 2 KB alias; guarded by bar2..bar4

    const int t    = threadIdx.x;
    const int lane = t & 63;
    const int wv   = t >> 6;
    const int llo  = lane & 15;
    const int lhi  = lane >> 4;
    const int b    = blockIdx.x >> 4;   // sample (16 blocks each)
    const int g    = blockIdx.x & 15;
    const int e    = __builtin_amdgcn_readfirstlane(obj[b]);
    const __bf16* w2e = w2b + (size_t)e * 65536;

    // ---- stage ALL of W2[e] into LDS once (128 KB), frag-linear layout ----
    #pragma unroll
    for (int it = 0; it < 16; ++it) {
        int c  = it * NT + wv * 64 + lane;        // chunk id 0..8191
        int kt = c >> 10, m = (c >> 2) & 255, sl = c & 3;
        GLOAD_LDS16(w2e + m * 256 + (kt * 4 + sl) * 8,
                    w2s + (it * NT + wv * 64) * 16);
    }

    const float* w1e = w1 + e * 1536;   // uniform bases -> scalar loads in L1
    const float* b1e = b1 + e * 256;
    const float  b3e = b3[e];
    f32x4 bv[2], wf[2];                 // b2 bias + w3 weights for this wave's 32 rows
    #pragma unroll
    for (int mt = 0; mt < 2; ++mt) {
        bv[mt] = *(const f32x4*)(b2 + e * 256 + wv * 32 + mt * 16 + lhi * 4);
        wf[mt] = *(const f32x4*)(w3 + e * 256 + wv * 32 + mt * 16 + lhi * 4);
    }
    const int nx = lane & 7;

    float xr[6];                        // chunk 0 inputs
    #pragma unroll
    for (int i = 0; i < 6; ++i)
        xr[i] = x[(size_t)(b * 6 + i) * V_TOTAL + g * (NV * 64) + lane];

    for (int iv = 0; iv < NV; ++iv) {
        const int v0 = (g * NV + iv) * 64;

        // ---- layer 1: h1t[pos][k] = relu(W1 x + b1); 4 chunks of 8 per wave ----
        {
            char* drow = h1t + lane * 512;
            #pragma unroll
            for (int q = 0; q < 4; ++q) {
                int m8 = wv * 4 + q;                  // 16B chunk (8 h-values)
                bf16x8 pack;
                #pragma unroll
                for (int j = 0; j < 8; ++j) {
                    int m = m8 * 8 + j;               // wave-uniform -> scalar operands
                    float a = b1e[m];
                    #pragma unroll
                    for (int i2 = 0; i2 < 6; ++i2)
                        a = fmaf(w1e[m * 6 + i2], xr[i2], a);
                    pack[j] = (__bf16)fmaxf(a, 0.f);
                }
                *(bf16x8*)(drow + ((m8 ^ nx) << 4)) = pack;
            }
        }
        __syncthreads();   // bar1: h1 ready; (iv==0: W2 staging drained too)

        if (iv + 1 < NV)   // prefetch next chunk's x under the MFMA phase
            #pragma unroll
            for (int i = 0; i < 6; ++i)
                xr[i] = x[(size_t)(b * 6 + i) * V_TOTAL + v0 + 64 + lane];

        // ---- layer 2: 64 MFMA/wave; A contiguous-LDS (0-conflict), B swizzled ----
        f32x4 acc[2][4];
        #pragma unroll
        for (int mt = 0; mt < 2; ++mt)
            #pragma unroll
            for (int nt = 0; nt < 4; ++nt) acc[mt][nt] = bv[mt];
        #pragma unroll
        for (int kt = 0; kt < 8; ++kt) {
            bf16x8 bb[4];
            #pragma unroll
            for (int nt = 0; nt < 4; ++nt) {          // B[k][n], ~2-way via swizzle
                int n = nt * 16 + llo;
                bb[nt] = *(const bf16x8*)(h1t + n * 512 + (((kt * 4 + lhi) ^ (n & 7)) << 4));
            }
            #pragma unroll
            for (int mt = 0; mt < 2; ++mt) {          // A: 64 lanes read contiguous 1 KB
                const bf16x8 aa = *(const bf16x8*)(
                    w2s + kt * 16384 + (wv * 128 + mt * 64 + llo * 4 + lhi) * 16);
                #pragma unroll
                for (int nt = 0; nt < 4; ++nt)
                    acc[mt][nt] = __builtin_amdgcn_mfma_f32_16x16x32_bf16(
                        aa, bb[nt], acc[mt][nt], 0, 0, 0);
            }
        }

        // ---- layer 3: p[nt] = this wave's 32-row partial of w3.relu(h2) ----
        float p[4];
        #pragma unroll
        for (int nt = 0; nt < 4; ++nt) {
            float s = 0.f;
            #pragma unroll
            for (int mt = 0; mt < 2; ++mt)
                #pragma unroll
                for (int j = 0; j < 4; ++j)
                    s = fmaf(wf[mt][j], fmaxf(acc[mt][nt][j], 0.f), s);
            s += __shfl_xor(s, 16, 64);
            s += __shfl_xor(s, 32, 64);
            p[nt] = s;                                // lanes 0-15: col nt*16+lane
        }
        __syncthreads();   // bar2: all h1t reads done -> red (alias) writable
        if (lane < 16)
            #pragma unroll
            for (int nt = 0; nt < 4; ++nt)
                red[wv * 64 + nt * 16 + lane] = p[nt];
        __syncthreads();   // bar3: red ready
        if (t < 64) {
            float s = b3e;
            #pragma unroll
            for (int w8 = 0; w8 < 8; ++w8) s += red[w8 * 64 + t];
            out[(size_t)b * V_TOTAL + v0 + t] = s;
        }
        __syncthreads();   // bar4: red reads done before next L1 overwrites h1t
    }
}

extern "C" void kernel_launch(void* const* d_in, const int* in_sizes, int n_in,
                              void* d_out, int out_size, void* d_ws, size_t ws_size,
                              hipStream_t stream) {
    const float* x   = (const float*)d_in[0];
    const int*   obj = (const int*)d_in[1];
    const float* w1  = (const float*)d_in[2];
    const float* b1  = (const float*)d_in[3];
    const float* w2  = (const float*)d_in[4];
    const float* b2  = (const float*)d_in[5];
    const float* w3  = (const float*)d_in[6];
    const float* b3  = (const float*)d_in[7];
    float*  out = (float*)d_out;
    __bf16* w2b = (__bf16*)d_ws;   // 8*256*256 bf16 = 1 MB

    // allow >64KB dynamic LDS (no-op if unsupported; ignore return)
    (void)hipFuncSetAttribute((const void*)fused_mlp,
                              hipFuncAttributeMaxDynamicSharedMemorySize, LDS_TOT);

    w2_to_bf16<<<2048, 256, 0, stream>>>(w2, w2b);
    fused_mlp<<<NBLK, NT, LDS_TOT, stream>>>(x, obj, w1, b1, b2, w3, b3, w2b, out);
}

// Round 12
// 119.663 us; speedup vs baseline: 11.2482x; 2.5863x over previous
//
#include <hip/hip_runtime.h>
#include <hip/hip_bf16.h>

typedef __bf16 bf16x8 __attribute__((ext_vector_type(8)));
typedef __bf16 bf16x4 __attribute__((ext_vector_type(4)));
typedef float  f32x4  __attribute__((ext_vector_type(4)));

#define V_TOTAL 32768
#define NT      512        // 8 waves; wave owns 32 M-rows in L2-phase, 8 positions in L1-phase
#define NV      32         // v-chunks of 64 positions per block
#define NBLK    256        // 1 block/CU (160 KiB LDS); 16 blocks per sample

#define W2_LDS  131072     // [8 kt][256 m][4 sl] chunks of 16B -> frag-linear A reads
#define H1_LDS  32768      // [64 pos][32 c] chunks, c = m8 ^ (pos&7)
#define LDS_TOT (W2_LDS + H1_LDS)   // 163840 = 160 KiB exactly

// async global->LDS, 16B/lane; LDS dest = wave-uniform base + lane*16
#define GLOAD_LDS16(g, l) __builtin_amdgcn_global_load_lds( \
    (const __attribute__((address_space(1))) void*)(g),     \
    (__attribute__((address_space(3))) void*)(l), 16, 0, 0)

// ---- prep: w2 fp32 -> bf16 (RNE) into workspace ----
__global__ void w2_to_bf16(const float* __restrict__ w2, __bf16* __restrict__ w2b) {
    int i = blockIdx.x * 256 + threadIdx.x;   // grid sized exactly: 8*256*256
    w2b[i] = (__bf16)w2[i];
}

__global__ __launch_bounds__(NT) void fused_mlp(
    const float* __restrict__ x,  const int* __restrict__ obj,
    const float* __restrict__ w1, const float* __restrict__ b1,
    const float* __restrict__ b2, const float* __restrict__ w3,
    const float* __restrict__ b3, const __bf16* __restrict__ w2b,
    float* __restrict__ out)
{
    extern __shared__ __align__(16) char smem[];
    char*  w2s = smem;            // A: chunk (kt*1024 + m*4 + sl) = W2[m][kt*32+sl*8 ..+8)
    char*  h1t = smem + W2_LDS;   // B: row pos, 16B chunk slot m8 ^ (pos&7)
    float* red = (float*)h1t;     // 2 KB alias; guarded by bar2..bar4

    const int t    = threadIdx.x;
    const int lane = t & 63;
    const int wv   = t >> 6;
    const int llo  = lane & 15;
    const int lhi  = lane >> 4;
    const int b    = blockIdx.x >> 4;   // sample (16 blocks each)
    const int g    = blockIdx.x & 15;
    const int e    = __builtin_amdgcn_readfirstlane(obj[b]);
    const __bf16* w2e = w2b + (size_t)e * 65536;

    // ---- stage ALL of W2[e] into LDS once (128 KB), frag-linear layout ----
    #pragma unroll
    for (int it = 0; it < 16; ++it) {
        int c  = it * NT + wv * 64 + lane;        // chunk id 0..8191
        int kt = c >> 10, m = (c >> 2) & 255, sl = c & 3;
        GLOAD_LDS16(w2e + m * 256 + (kt * 4 + sl) * 8,
                    w2s + (it * NT + wv * 64) * 16);
    }

    // ---- L1 weights REGISTER-RESIDENT: lane owns m = lane*4 .. lane*4+3 ----
    // (R11 bug: per-chunk w1 loads were per-lane VMEM -> ~50 MB HBM re-reads)
    f32x4 w1q[6];                       // 24 floats = rows lane*4..+3 of W1[e]
    #pragma unroll
    for (int i = 0; i < 6; ++i)
        w1q[i] = *(const f32x4*)(w1 + e * 1536 + lane * 24 + i * 4);
    const f32x4 b1q = *(const f32x4*)(b1 + e * 256 + lane * 4);
    const float b3e = b3[e];
    f32x4 bv[2], wf[2];                 // b2 bias + w3 weights (L2-phase rows)
    #pragma unroll
    for (int mt = 0; mt < 2; ++mt) {
        bv[mt] = *(const f32x4*)(b2 + e * 256 + wv * 32 + mt * 16 + lhi * 4);
        wf[mt] = *(const f32x4*)(w3 + e * 256 + wv * 32 + mt * 16 + lhi * 4);
    }
    const float* xb = x + (size_t)b * 6 * V_TOTAL + wv * 8;  // wave's 8 positions

    for (int iv = 0; iv < NV; ++iv) {
        const int v0 = (g * NV + iv) * 64;

        // ---- layer 1: wave computes its 8 positions x all 256 m (4 m/lane) ----
        #pragma unroll
        for (int half = 0; half < 2; ++half) {
            f32x4 xq[6];                          // wave-uniform -> scalar loads
            #pragma unroll
            for (int i = 0; i < 6; ++i)
                xq[i] = *(const f32x4*)(xb + i * V_TOTAL + v0 + half * 4);
            #pragma unroll
            for (int pp = 0; pp < 4; ++pp) {
                const int p = wv * 8 + half * 4 + pp;
                bf16x4 pk;
                #pragma unroll
                for (int r = 0; r < 4; ++r) {
                    float a = b1q[r];
                    #pragma unroll
                    for (int i = 0; i < 6; ++i)
                        a = fmaf(w1q[(r * 6 + i) >> 2][(r * 6 + i) & 3], xq[i][pp], a);
                    pk[r] = (__bf16)fmaxf(a, 0.f);
                }
                *(bf16x4*)(h1t + p * 512 + ((((lane >> 1) ^ (p & 7))) << 4)
                           + (lane & 1) * 8) = pk;
            }
        }
        __syncthreads();   // bar1: h1 ready; (iv==0: W2 staging drained too)

        // ---- layer 2: 64 MFMA/wave; A contiguous-LDS (0-conflict), B swizzled ----
        f32x4 acc[2][4];
        #pragma unroll
        for (int mt = 0; mt < 2; ++mt)
            #pragma unroll
            for (int nt = 0; nt < 4; ++nt) acc[mt][nt] = bv[mt];
        __builtin_amdgcn_s_setprio(1);
        #pragma unroll
        for (int kt = 0; kt < 8; ++kt) {
            bf16x8 bb[4];
            #pragma unroll
            for (int nt = 0; nt < 4; ++nt) {          // B[k][n], ~2-way via swizzle
                int n = nt * 16 + llo;
                bb[nt] = *(const bf16x8*)(h1t + n * 512 + (((kt * 4 + lhi) ^ (n & 7)) << 4));
            }
            #pragma unroll
            for (int mt = 0; mt < 2; ++mt) {          // A: 64 lanes read contiguous 1 KB
                const bf16x8 aa = *(const bf16x8*)(
                    w2s + kt * 16384 + (wv * 128 + mt * 64 + llo * 4 + lhi) * 16);
                #pragma unroll
                for (int nt = 0; nt < 4; ++nt)
                    acc[mt][nt] = __builtin_amdgcn_mfma_f32_16x16x32_bf16(
                        aa, bb[nt], acc[mt][nt], 0, 0, 0);
            }
        }
        __builtin_amdgcn_s_setprio(0);

        // ---- layer 3: p[nt] = this wave's 32-row partial of w3.relu(h2) ----
        float p[4];
        #pragma unroll
        for (int nt = 0; nt < 4; ++nt) {
            float s = 0.f;
            #pragma unroll
            for (int mt = 0; mt < 2; ++mt)
                #pragma unroll
                for (int j = 0; j < 4; ++j)
                    s = fmaf(wf[mt][j], fmaxf(acc[mt][nt][j], 0.f), s);
            s += __shfl_xor(s, 16, 64);
            s += __shfl_xor(s, 32, 64);
            p[nt] = s;                                // lanes 0-15: col nt*16+lane
        }
        __syncthreads();   // bar2: all h1t reads done -> red (alias) writable
        if (lane < 16)
            #pragma unroll
            for (int nt = 0; nt < 4; ++nt)
                red[wv * 64 + nt * 16 + lane] = p[nt];
        __syncthreads();   // bar3: red ready
        if (t < 64) {
            float s = b3e;
            #pragma unroll
            for (int w8 = 0; w8 < 8; ++w8) s += red[w8 * 64 + t];
            out[(size_t)b * V_TOTAL + v0 + t] = s;
        }
        __syncthreads();   // bar4: red reads done before next L1 overwrites h1t
    }
}

extern "C" void kernel_launch(void* const* d_in, const int* in_sizes, int n_in,
                              void* d_out, int out_size, void* d_ws, size_t ws_size,
                              hipStream_t stream) {
    const float* x   = (const float*)d_in[0];
    const int*   obj = (const int*)d_in[1];
    const float* w1  = (const float*)d_in[2];
    const float* b1  = (const float*)d_in[3];
    const float* w2  = (const float*)d_in[4];
    const float* b2  = (const float*)d_in[5];
    const float* w3  = (const float*)d_in[6];
    const float* b3  = (const float*)d_in[7];
    float*  out = (float*)d_out;
    __bf16* w2b = (__bf16*)d_ws;   // 8*256*256 bf16 = 1 MB

    (void)hipFuncSetAttribute((const void*)fused_mlp,
                              hipFuncAttributeMaxDynamicSharedMemorySize, LDS_TOT);

    w2_to_bf16<<<2048, 256, 0, stream>>>(w2, w2b);
    fused_mlp<<<NBLK, NT, LDS_TOT, stream>>>(x, obj, w1, b1, b2, w3, b3, w2b, out);
}

// Round 13
// 112.711 us; speedup vs baseline: 11.9420x; 1.0617x over previous
//
#include <hip/hip_runtime.h>
#include <hip/hip_bf16.h>

typedef __bf16 bf16x8 __attribute__((ext_vector_type(8)));
typedef __bf16 bf16x4 __attribute__((ext_vector_type(4)));
typedef float  f32x4  __attribute__((ext_vector_type(4)));

#define V_TOTAL 32768
#define NT      512        // 8 waves; wave owns 32 M-rows in L2-phase, 8 positions in L1-phase
#define NV      32         // v-chunks of 64 positions per block
#define NBLK    256        // 1 block/CU (160 KiB LDS); 16 blocks per sample

#define W2_LDS  131072     // [8 kt][16 mtile][4 koct][16 row] 16B chunks -> lane-LINEAR A reads
#define H1_LDS  32768      // [64 pos][32 c] chunks, c = m8 ^ (pos&7)
#define LDS_TOT (W2_LDS + H1_LDS)   // 163840 = 160 KiB exactly

// async global->LDS, 16B/lane; LDS dest = wave-uniform base + lane*16
#define GLOAD_LDS16(g, l) __builtin_amdgcn_global_load_lds( \
    (const __attribute__((address_space(1))) void*)(g),     \
    (__attribute__((address_space(3))) void*)(l), 16, 0, 0)

// ---- prep: w2 fp32 -> bf16 (RNE) into workspace ----
__global__ void w2_to_bf16(const float* __restrict__ w2, __bf16* __restrict__ w2b) {
    int i = blockIdx.x * 256 + threadIdx.x;   // grid sized exactly: 8*256*256
    w2b[i] = (__bf16)w2[i];
}

__global__ __launch_bounds__(NT) void fused_mlp(
    const float* __restrict__ x,  const int* __restrict__ obj,
    const float* __restrict__ w1, const float* __restrict__ b1,
    const float* __restrict__ b2, const float* __restrict__ w3,
    const float* __restrict__ b3, const __bf16* __restrict__ w2b,
    float* __restrict__ out)
{
    extern __shared__ __align__(16) char smem[];
    char*  w2s = smem;            // A: chunk (kt*1024 + mtile*64 + koct*16 + row)
                                  //    holds W2[mtile*16+row][kt*32 + koct*8 ..+8)
                                  //    -> lane l reads chunk (mtile*64 + l): LINEAR, 0-conflict
    char*  h1t = smem + W2_LDS;   // B: row pos, 16B chunk slot m8 ^ (pos&7)
    float* red = (float*)h1t;     // 2 KB alias; guarded by bar2..bar4

    const int t    = threadIdx.x;
    const int lane = t & 63;
    const int wv   = t >> 6;
    const int llo  = lane & 15;
    const int lhi  = lane >> 4;
    const int b    = blockIdx.x >> 4;   // sample (16 blocks each)
    const int g    = blockIdx.x & 15;
    const int e    = __builtin_amdgcn_readfirstlane(obj[b]);
    const __bf16* w2e = w2b + (size_t)e * 65536;

    // ---- stage ALL of W2[e] into LDS once (128 KB), lane-linear frag layout ----
    #pragma unroll
    for (int it = 0; it < 16; ++it) {
        int c    = it * NT + wv * 64 + lane;      // chunk id 0..8191
        int kt   = c >> 10;
        int mt16 = (c >> 6) & 15;                 // 16-row tile
        int ko   = (c >> 4) & 3;                  // k-octet within kt
        int row  = c & 15;
        GLOAD_LDS16(w2e + (mt16 * 16 + row) * 256 + kt * 32 + ko * 8,
                    w2s + (it * NT + wv * 64) * 16);
    }

    // ---- L1 weights REGISTER-RESIDENT: lane owns m = lane*4 .. lane*4+3 ----
    f32x4 w1q[6];                       // 24 floats = rows lane*4..+3 of W1[e]
    #pragma unroll
    for (int i = 0; i < 6; ++i)
        w1q[i] = *(const f32x4*)(w1 + e * 1536 + lane * 24 + i * 4);
    const f32x4 b1q = *(const f32x4*)(b1 + e * 256 + lane * 4);
    const float b3e = b3[e];
    f32x4 bv[2], wf[2];                 // b2 bias + w3 weights (L2-phase rows)
    #pragma unroll
    for (int mt = 0; mt < 2; ++mt) {
        bv[mt] = *(const f32x4*)(b2 + e * 256 + wv * 32 + mt * 16 + lhi * 4);
        wf[mt] = *(const f32x4*)(w3 + e * 256 + wv * 32 + mt * 16 + lhi * 4);
    }
    const float* xb = x + (size_t)b * 6 * V_TOTAL + wv * 8;  // wave's 8 positions

    for (int iv = 0; iv < NV; ++iv) {
        const int v0 = (g * NV + iv) * 64;

        // ---- layer 1: wave computes its 8 positions x all 256 m (4 m/lane) ----
        #pragma unroll
        for (int half = 0; half < 2; ++half) {
            f32x4 xq[6];                          // wave-uniform -> scalar loads
            #pragma unroll
            for (int i = 0; i < 6; ++i)
                xq[i] = *(const f32x4*)(xb + i * V_TOTAL + v0 + half * 4);
            #pragma unroll
            for (int pp = 0; pp < 4; ++pp) {
                const int p = wv * 8 + half * 4 + pp;
                bf16x4 pk;
                #pragma unroll
                for (int r = 0; r < 4; ++r) {
                    float a = b1q[r];
                    #pragma unroll
                    for (int i = 0; i < 6; ++i)
                        a = fmaf(w1q[(r * 6 + i) >> 2][(r * 6 + i) & 3], xq[i][pp], a);
                    pk[r] = (__bf16)fmaxf(a, 0.f);
                }
                *(bf16x4*)(h1t + p * 512 + ((((lane >> 1) ^ (p & 7))) << 4)
                           + (lane & 1) * 8) = pk;
            }
        }
        __syncthreads();   // bar1: h1 ready; (iv==0: W2 staging drained too)

        // ---- layer 2: 64 MFMA/wave; A lane-linear LDS (0-conflict), B swizzled ----
        f32x4 acc[2][4];
        #pragma unroll
        for (int mt = 0; mt < 2; ++mt)
            #pragma unroll
            for (int nt = 0; nt < 4; ++nt) acc[mt][nt] = bv[mt];
        __builtin_amdgcn_s_setprio(1);
        #pragma unroll
        for (int kt = 0; kt < 8; ++kt) {
            bf16x8 bb[4];
            #pragma unroll
            for (int nt = 0; nt < 4; ++nt) {          // B[k][n], ~2-way via swizzle
                int n = nt * 16 + llo;
                bb[nt] = *(const bf16x8*)(h1t + n * 512 + (((kt * 4 + lhi) ^ (n & 7)) << 4));
            }
            #pragma unroll
            for (int mt = 0; mt < 2; ++mt) {
                // A frag for lane l: row llo of tile (wv*2+mt), k-octet lhi
                // stored at chunk (wv*2+mt)*64 + lhi*16 + llo = tile*64 + lane -> linear
                const bf16x8 aa = *(const bf16x8*)(
                    w2s + kt * 16384 + ((wv * 2 + mt) * 64 + lane) * 16);
                #pragma unroll
                for (int nt = 0; nt < 4; ++nt)
                    acc[mt][nt] = __builtin_amdgcn_mfma_f32_16x16x32_bf16(
                        aa, bb[nt], acc[mt][nt], 0, 0, 0);
            }
        }
        __builtin_amdgcn_s_setprio(0);

        // ---- layer 3: p[nt] = this wave's 32-row partial of w3.relu(h2) ----
        float p[4];
        #pragma unroll
        for (int nt = 0; nt < 4; ++nt) {
            float s = 0.f;
            #pragma unroll
            for (int mt = 0; mt < 2; ++mt)
                #pragma unroll
                for (int j = 0; j < 4; ++j)
                    s = fmaf(wf[mt][j], fmaxf(acc[mt][nt][j], 0.f), s);
            s += __shfl_xor(s, 16, 64);
            s += __shfl_xor(s, 32, 64);
            p[nt] = s;                                // lanes 0-15: col nt*16+lane
        }
        __syncthreads();   // bar2: all h1t reads done -> red (alias) writable
        if (lane < 16)
            #pragma unroll
            for (int nt = 0; nt < 4; ++nt)
                red[wv * 64 + nt * 16 + lane] = p[nt];
        __syncthreads();   // bar3: red ready
        if (t < 64) {
            float s = b3e;
            #pragma unroll
            for (int w8 = 0; w8 < 8; ++w8) s += red[w8 * 64 + t];
            out[(size_t)b * V_TOTAL + v0 + t] = s;
        }
        __syncthreads();   // bar4: red reads done before next L1 overwrites h1t
    }
}

extern "C" void kernel_launch(void* const* d_in, const int* in_sizes, int n_in,
                              void* d_out, int out_size, void* d_ws, size_t ws_size,
                              hipStream_t stream) {
    const float* x   = (const float*)d_in[0];
    const int*   obj = (const int*)d_in[1];
    const float* w1  = (const float*)d_in[2];
    const float* b1  = (const float*)d_in[3];
    const float* w2  = (const float*)d_in[4];
    const float* b2  = (const float*)d_in[5];
    const float* w3  = (const float*)d_in[6];
    const float* b3  = (const float*)d_in[7];
    float*  out = (float*)d_out;
    __bf16* w2b = (__bf16*)d_ws;   // 8*256*256 bf16 = 1 MB

    (void)hipFuncSetAttribute((const void*)fused_mlp,
                              hipFuncAttributeMaxDynamicSharedMemorySize, LDS_TOT);

    w2_to_bf16<<<2048, 256, 0, stream>>>(w2, w2b);
    fused_mlp<<<NBLK, NT, LDS_TOT, stream>>>(x, obj, w1, b1, b2, w3, b3, w2b, out);
}

// Round 14
// 93.796 us; speedup vs baseline: 14.3503x; 1.2017x over previous
//
#include <hip/hip_runtime.h>
#include <hip/hip_bf16.h>

typedef __bf16 bf16x8 __attribute__((ext_vector_type(8)));
typedef __bf16 bf16x4 __attribute__((ext_vector_type(4)));
typedef float  f32x4  __attribute__((ext_vector_type(4)));

#define V_TOTAL 32768
#define NT      512        // 8 waves; wave owns 32 M-rows (L2) / 2 m-tiles (L1)
#define NV      32         // v-chunks of 64 positions per block
#define NBLK    256        // 1 block/CU (160 KiB LDS); 16 blocks per sample

#define W2_LDS  131072     // [8 kt][16 mtile][4 koct][16 row] 16B chunks -> lane-LINEAR A reads
#define H1_LDS  32768      // [64 pos][32 c] chunks, c = m8 ^ (pos&7)
#define LDS_TOT (W2_LDS + H1_LDS)   // 163840 = 160 KiB exactly

// async global->LDS, 16B/lane; LDS dest = wave-uniform base + lane*16
#define GLOAD_LDS16(g, l) __builtin_amdgcn_global_load_lds( \
    (const __attribute__((address_space(1))) void*)(g),     \
    (__attribute__((address_space(3))) void*)(l), 16, 0, 0)

// ---- prep: w2 fp32 -> bf16 (RNE) into workspace ----
__global__ void w2_to_bf16(const float* __restrict__ w2, __bf16* __restrict__ w2b) {
    int i = blockIdx.x * 256 + threadIdx.x;   // grid sized exactly: 8*256*256
    w2b[i] = (__bf16)w2[i];
}

__global__ __launch_bounds__(NT) void fused_mlp(
    const float* __restrict__ x,  const int* __restrict__ obj,
    const float* __restrict__ w1, const float* __restrict__ b1,
    const float* __restrict__ b2, const float* __restrict__ w3,
    const float* __restrict__ b3, const __bf16* __restrict__ w2b,
    float* __restrict__ out)
{
    extern __shared__ __align__(16) char smem[];
    char*  w2s = smem;            // A: chunk (kt*1024 + mtile*64 + koct*16 + row) -> lane-linear
    char*  h1t = smem + W2_LDS;   // B: row pos, 16B chunk slot m8 ^ (pos&7)
    float* red = (float*)h1t;     // 2 KB alias; guarded by bar2..bar4

    const int t    = threadIdx.x;
    const int lane = t & 63;
    const int wv   = t >> 6;
    const int llo  = lane & 15;
    const int lhi  = lane >> 4;
    const int b    = blockIdx.x >> 4;   // sample (16 blocks each)
    const int g    = blockIdx.x & 15;
    const int e    = __builtin_amdgcn_readfirstlane(obj[b]);
    const __bf16* w2e = w2b + (size_t)e * 65536;

    // ---- stage ALL of W2[e] into LDS once (128 KB), lane-linear frag layout ----
    #pragma unroll
    for (int it = 0; it < 16; ++it) {
        int c    = it * NT + wv * 64 + lane;      // chunk id 0..8191
        int kt   = c >> 10;
        int mt16 = (c >> 6) & 15;
        int ko   = (c >> 4) & 3;
        int row  = c & 15;
        GLOAD_LDS16(w2e + (mt16 * 16 + row) * 256 + kt * 32 + ko * 8,
                    w2s + (it * NT + wv * 64) * 16);
    }

    // ---- L1 as MFMA: W1 A-frags + b1 C-init frags, resident ----
    // A-frag: lane holds A[row=llo][k=lhi*8+j]; k>=6 and lhi>0 are ZERO so the
    // x B-frag needs no masking (0 * garbage = 0).
    const float* w1e = w1 + e * 1536;
    bf16x8 aa1[2];
    f32x4  b1f[2];
    #pragma unroll
    for (int mt2 = 0; mt2 < 2; ++mt2) {
        const int m0 = (2 * wv + mt2) * 16;
        bf16x8 v = {};
        if (lhi == 0)
            #pragma unroll
            for (int j = 0; j < 6; ++j) v[j] = (__bf16)w1e[(m0 + llo) * 6 + j];
        aa1[mt2] = v;
        b1f[mt2] = *(const f32x4*)(b1 + e * 256 + m0 + lhi * 4);
    }
    const float b3e = b3[e];
    f32x4 bv[2], wf[2];                 // b2 bias + w3 weights (L2-phase rows)
    #pragma unroll
    for (int mt = 0; mt < 2; ++mt) {
        bv[mt] = *(const f32x4*)(b2 + e * 256 + wv * 32 + mt * 16 + lhi * 4);
        wf[mt] = *(const f32x4*)(w3 + e * 256 + wv * 32 + mt * 16 + lhi * 4);
    }
    const float* xe = x + (size_t)b * 6 * V_TOTAL;

    // ---- chunk-0 x prefetch: xr[pt][i] = x[i][v0 + pt*16 + llo] ----
    float xr[4][6];
    #pragma unroll
    for (int pt = 0; pt < 4; ++pt)
        #pragma unroll
        for (int i = 0; i < 6; ++i)
            xr[pt][i] = xe[i * V_TOTAL + g * (NV * 64) + pt * 16 + llo];

    for (int iv = 0; iv < NV; ++iv) {
        const int v0 = (g * NV + iv) * 64;

        // ---- layer 1 (MFMA): h1[m][pos] = relu(W1 x + b1), 2 mt x 4 pt ----
        {
            bf16x8 bb1[4];
            #pragma unroll
            for (int pt = 0; pt < 4; ++pt) {          // B-frag: x bf16 (k>=6 junk ok)
                bf16x8 v = {};
                #pragma unroll
                for (int i = 0; i < 6; ++i) v[i] = (__bf16)xr[pt][i];
                bb1[pt] = v;
            }
            #pragma unroll
            for (int mt2 = 0; mt2 < 2; ++mt2) {
                const int mc0 = (2 * wv + mt2) * 2 + (lhi >> 1);  // m-octet
                #pragma unroll
                for (int pt = 0; pt < 4; ++pt) {
                    f32x4 h = __builtin_amdgcn_mfma_f32_16x16x32_bf16(
                        aa1[mt2], bb1[pt], b1f[mt2], 0, 0, 0);
                    bf16x4 pk;
                    #pragma unroll
                    for (int r = 0; r < 4; ++r) pk[r] = (__bf16)fmaxf(h[r], 0.f);
                    const int p = pt * 16 + llo;      // position (C col)
                    *(bf16x4*)(h1t + p * 512 + ((mc0 ^ (p & 7)) << 4)
                               + (lhi & 1) * 8) = pk;
                }
            }
        }
        if (iv + 1 < NV)   // issue next chunk's x loads; latency hides under MFMA phase
            #pragma unroll
            for (int pt = 0; pt < 4; ++pt)
                #pragma unroll
                for (int i = 0; i < 6; ++i)
                    xr[pt][i] = xe[i * V_TOTAL + v0 + 64 + pt * 16 + llo];
        __syncthreads();   // bar1: h1 ready; (iv==0: W2 staging drained too)

        // ---- layer 2: 64 MFMA/wave; A lane-linear LDS (0-conflict), B swizzled ----
        f32x4 acc[2][4];
        #pragma unroll
        for (int mt = 0; mt < 2; ++mt)
            #pragma unroll
            for (int nt = 0; nt < 4; ++nt) acc[mt][nt] = bv[mt];
        __builtin_amdgcn_s_setprio(1);
        #pragma unroll
        for (int kt = 0; kt < 8; ++kt) {
            bf16x8 bb[4];
            #pragma unroll
            for (int nt = 0; nt < 4; ++nt) {          // B[k][n], ~2-way via swizzle
                int n = nt * 16 + llo;
                bb[nt] = *(const bf16x8*)(h1t + n * 512 + (((kt * 4 + lhi) ^ (n & 7)) << 4));
            }
            #pragma unroll
            for (int mt = 0; mt < 2; ++mt) {
                const bf16x8 aw = *(const bf16x8*)(   // linear: chunk tile*64 + lane
                    w2s + kt * 16384 + ((wv * 2 + mt) * 64 + lane) * 16);
                #pragma unroll
                for (int nt = 0; nt < 4; ++nt)
                    acc[mt][nt] = __builtin_amdgcn_mfma_f32_16x16x32_bf16(
                        aw, bb[nt], acc[mt][nt], 0, 0, 0);
            }
        }
        __builtin_amdgcn_s_setprio(0);

        // ---- layer 3: p[nt] = this wave's 32-row partial of w3.relu(h2) ----
        float p[4];
        #pragma unroll
        for (int nt = 0; nt < 4; ++nt) {
            float s = 0.f;
            #pragma unroll
            for (int mt = 0; mt < 2; ++mt)
                #pragma unroll
                for (int j = 0; j < 4; ++j)
                    s = fmaf(wf[mt][j], fmaxf(acc[mt][nt][j], 0.f), s);
            s += __shfl_xor(s, 16, 64);
            s += __shfl_xor(s, 32, 64);
            p[nt] = s;                                // lanes 0-15: col nt*16+lane
        }
        __syncthreads();   // bar2: all h1t reads done -> red (alias) writable
        if (lane < 16)
            #pragma unroll
            for (int nt = 0; nt < 4; ++nt)
                red[wv * 64 + nt * 16 + lane] = p[nt];
        __syncthreads();   // bar3: red ready
        if (t < 64) {
            float s = b3e;
            #pragma unroll
            for (int w8 = 0; w8 < 8; ++w8) s += red[w8 * 64 + t];
            out[(size_t)b * V_TOTAL + v0 + t] = s;
        }
        __syncthreads();   // bar4: red reads done before next L1 overwrites h1t
    }
}

extern "C" void kernel_launch(void* const* d_in, const int* in_sizes, int n_in,
                              void* d_out, int out_size, void* d_ws, size_t ws_size,
                              hipStream_t stream) {
    const float* x   = (const float*)d_in[0];
    const int*   obj = (const int*)d_in[1];
    const float* w1  = (const float*)d_in[2];
    const float* b1  = (const float*)d_in[3];
    const float* w2  = (const float*)d_in[4];
    const float* b2  = (const float*)d_in[5];
    const float* w3  = (const float*)d_in[6];
    const float* b3  = (const float*)d_in[7];
    float*  out = (float*)d_out;
    __bf16* w2b = (__bf16*)d_ws;   // 8*256*256 bf16 = 1 MB

    (void)hipFuncSetAttribute((const void*)fused_mlp,
                              hipFuncAttributeMaxDynamicSharedMemorySize, LDS_TOT);

    w2_to_bf16<<<2048, 256, 0, stream>>>(w2, w2b);
    fused_mlp<<<NBLK, NT, LDS_TOT, stream>>>(x, obj, w1, b1, b2, w3, b3, w2b, out);
}